// Round 2
// baseline (640.957 us; speedup 1.0000x reference)
//
#include <hip/hip_runtime.h>
#include <hip/hip_bf16.h>

#define BB 2
#define NN 2048
#define DD 768
#define EE 8
#define FF 3072
#define TOK (BB*NN)       // 4096
#define ROWS_CAP 9216     // 8192 slots + 8*128 alignment pad
#define TILES 72          // ROWS_CAP / 128
#define LDST 40           // padded LDS row stride (32 + 8)

typedef __attribute__((ext_vector_type(8))) __bf16 bf16x8;
typedef __attribute__((ext_vector_type(4))) float floatx4;

// ---------- ws layout (bytes) ----------
// small control region
#define OFF_CTRL    0ull                    // int[96]: cnt@0, cursor@8, base@16, tile_expert@24
#define OFF_V       1024ull                 // float[4096]
#define OFF_TOKE    17408ull                // int[8192]
#define OFF_TOKW    50176ull                // float[8192]
#define OFF_ROWTOK  82944ull                // int[9216]
#define OFF_ROWW    119808ull               // float[9216]
#define OFF_SLOT    156672ull               // int[8192]
#define OFF_FEATS   189440ull               // float[8192]
// big buffers
#define OFF_W2BF    222208ull               // ushort[8*3072*768] = 37,748,736 B
#define OFF_XBF     37970944ull             // ushort[4096*768]   = 6,291,456 B
#define OFF_W1BF    44262400ull             // ushort[8*768*3072] = 37,748,736 B
#define OFF_H       82011136ull             // ushort[9216*3072]  = 56,623,104 B -> end 138,634,240
#define OFF_Y       OFF_XBF                 // float[9216*768] = 28,311,552 B, aliases dead XBF+W1BF

__device__ __forceinline__ ushort f2b(float f) {
    union { float f; unsigned int i; } v; v.f = f;
    unsigned int u = v.i;
    unsigned int r = (u + 0x7FFFu + ((u >> 16) & 1u)) >> 16;
    return (ushort)r;
}
__device__ __forceinline__ unsigned int pk2(float lo, float hi) {
    union { float f; unsigned int u; } a, b;
    a.f = lo; b.f = hi;
    unsigned int ra = ((a.u + 0x7FFFu + ((a.u >> 16) & 1u)) >> 16) & 0xFFFFu;
    unsigned int rb = (b.u + 0x7FFFu + ((b.u >> 16) & 1u)) & 0xFFFF0000u;
    return ra | rb;
}
__device__ __forceinline__ float gelu_f(float x) {
    float z = 0.7978845608028654f * x * (1.f + 0.044715f * x * x);
    z = fminf(fmaxf(z, -12.f), 12.f);
    float e = __expf(2.f * z);
    return 0.5f * x * (1.f + (e - 1.f) / (e + 1.f));
}

// ---------- complex / Mobius helpers ----------
struct cplx { float x, y; };
__device__ __forceinline__ cplx cmulc(cplx a, cplx b) { return {a.x*b.x - a.y*b.y, a.x*b.y + a.y*b.x}; }
__device__ __forceinline__ cplx caddc(cplx a, cplx b) { return {a.x + b.x, a.y + b.y}; }
__device__ __forceinline__ cplx cdivc(cplx a, cplx b) {
    float s = 1.f / (b.x*b.x + b.y*b.y);
    return {(a.x*b.x + a.y*b.y)*s, (a.y*b.x - a.x*b.y)*s};
}
struct mob { cplx m00, m01, m10, m11; };
__device__ __forceinline__ mob mmul(const mob& A, const mob& B) {  // A*B
    mob C;
    C.m00 = caddc(cmulc(A.m00, B.m00), cmulc(A.m01, B.m10));
    C.m01 = caddc(cmulc(A.m00, B.m01), cmulc(A.m01, B.m11));
    C.m10 = caddc(cmulc(A.m10, B.m00), cmulc(A.m11, B.m10));
    C.m11 = caddc(cmulc(A.m10, B.m01), cmulc(A.m11, B.m11));
    return C;
}
__device__ __forceinline__ void mnorm(mob& A) {
    float s = fabsf(A.m00.x);
    s = fmaxf(s, fabsf(A.m00.y)); s = fmaxf(s, fabsf(A.m01.x)); s = fmaxf(s, fabsf(A.m01.y));
    s = fmaxf(s, fabsf(A.m10.x)); s = fmaxf(s, fabsf(A.m10.y)); s = fmaxf(s, fabsf(A.m11.x));
    s = fmaxf(s, fabsf(A.m11.y));
    float r = 1.f / fmaxf(s, 1e-30f);
    A.m00.x *= r; A.m00.y *= r; A.m01.x *= r; A.m01.y *= r;
    A.m10.x *= r; A.m10.y *= r; A.m11.x *= r; A.m11.y *= r;
}
// P -> [[a,-1],[1,0]] * P
__device__ __forceinline__ mob mstep(cplx a, const mob& P) {
    mob C;
    C.m00 = {a.x*P.m00.x - a.y*P.m00.y - P.m10.x, a.x*P.m00.y + a.y*P.m00.x - P.m10.y};
    C.m01 = {a.x*P.m01.x - a.y*P.m01.y - P.m11.x, a.x*P.m01.y + a.y*P.m01.x - P.m11.y};
    C.m10 = P.m00; C.m11 = P.m01;
    return C;
}
__device__ __forceinline__ void mstore(float* s, const mob& A) {
    s[0]=A.m00.x; s[1]=A.m00.y; s[2]=A.m01.x; s[3]=A.m01.y;
    s[4]=A.m10.x; s[5]=A.m10.y; s[6]=A.m11.x; s[7]=A.m11.y;
}
__device__ __forceinline__ mob mload(const float* s) {
    mob A;
    A.m00 = {s[0], s[1]}; A.m01 = {s[2], s[3]};
    A.m10 = {s[4], s[5]}; A.m11 = {s[6], s[7]};
    return A;
}

// ---------- K0: zero control ----------
__global__ void zero_ctrl_kernel(int* ctrl) {
    int tid = threadIdx.x;
    if (tid < 16) ctrl[tid] = 0;   // cnt[8] + cursor[8]
}

// ---------- K0b: fp32 -> bf16 bulk convert (8 elems/thread) ----------
__global__ __launch_bounds__(256) void cvt_kernel(
    const float* __restrict__ src, ushort* __restrict__ dst, int n8)
{
    int i = blockIdx.x * 256 + threadIdx.x;
    if (i >= n8) return;
    const float4* s = ((const float4*)src) + (size_t)i * 2;
    float4 a = s[0], b = s[1];
    uint4 o;
    o.x = pk2(a.x, a.y); o.y = pk2(a.z, a.w);
    o.z = pk2(b.x, b.y); o.w = pk2(b.z, b.w);
    *(((uint4*)dst) + i) = o;
}

// ---------- K1: routing (one wave per token), fp32 inputs ----------
__global__ __launch_bounds__(256) void routing_kernel(
    const float* __restrict__ x, const float* __restrict__ v_w, const float* __restrict__ v_b,
    const float* __restrict__ gate_w, const float* __restrict__ gate_b,
    float* __restrict__ v_out, int* __restrict__ tok_e, float* __restrict__ tok_w,
    int* __restrict__ ctrl)
{
    int wave = threadIdx.x >> 6, lane = threadIdx.x & 63;
    int t = blockIdx.x * 4 + wave;
    const float* xr = x + (size_t)t * DD;
    float av = 0.f;
    float ag[8] = {0.f, 0.f, 0.f, 0.f, 0.f, 0.f, 0.f, 0.f};
    #pragma unroll
    for (int i = 0; i < 12; i++) {
        int d = lane + 64 * i;
        float xv = xr[d];
        av += xv * v_w[d];
        const float4* g = (const float4*)(gate_w + d * 8);
        float4 g0 = g[0], g1 = g[1];
        ag[0] += xv * g0.x; ag[1] += xv * g0.y; ag[2] += xv * g0.z; ag[3] += xv * g0.w;
        ag[4] += xv * g1.x; ag[5] += xv * g1.y; ag[6] += xv * g1.z; ag[7] += xv * g1.w;
    }
    #pragma unroll
    for (int off = 32; off >= 1; off >>= 1) {
        av += __shfl_xor(av, off);
        #pragma unroll
        for (int e = 0; e < 8; e++) ag[e] += __shfl_xor(ag[e], off);
    }
    if (lane == 0) {
        float vv = av + v_b[0];
        vv = fminf(fmaxf(vv, -3.f), 3.f);
        v_out[t] = vv;
        float lg[8];
        #pragma unroll
        for (int e = 0; e < 8; e++) lg[e] = ag[e] + gate_b[e];
        int e0 = 0;
        #pragma unroll
        for (int e = 1; e < 8; e++) if (lg[e] > lg[e0]) e0 = e;
        int e1 = -1;
        #pragma unroll
        for (int e = 0; e < 8; e++) if (e != e0 && (e1 < 0 || lg[e] > lg[e1])) e1 = e;
        float w0 = 1.f / (1.f + __expf(lg[e1] - lg[e0]));
        tok_e[2*t] = e0; tok_e[2*t+1] = e1;
        tok_w[2*t] = w0; tok_w[2*t+1] = 1.f - w0;
        atomicAdd(&ctrl[e0], 1);
        atomicAdd(&ctrl[e1], 1);
    }
}

// ---------- K2: bases, tile map, row_token init ----------
__global__ void setup_kernel(int* __restrict__ ctrl, int* __restrict__ row_token) {
    int tid = threadIdx.x;
    if (tid == 0) {
        int* cnt  = ctrl;
        int* base = ctrl + 16;
        int* te   = ctrl + 24;
        for (int i = 0; i < TILES; i++) te[i] = -1;
        int b = 0;
        for (int e = 0; e < EE; e++) {
            base[e] = b;
            int tiles = (cnt[e] + 127) >> 7;
            int t0 = b >> 7;
            for (int i = 0; i < tiles; i++) te[t0 + i] = e;
            b += tiles << 7;
        }
    }
    for (int p = tid; p < ROWS_CAP; p += 256) row_token[p] = -1;
}

// ---------- K3: scatter tokens into expert rows ----------
__global__ __launch_bounds__(256) void scatter_kernel(
    const int* __restrict__ tok_e, const float* __restrict__ tok_w,
    int* __restrict__ ctrl, int* __restrict__ row_token, float* __restrict__ row_w,
    int* __restrict__ slot)
{
    int t = blockIdx.x * 256 + threadIdx.x;
    #pragma unroll
    for (int k = 0; k < 2; k++) {
        int e = tok_e[2*t + k];
        int p = ctrl[16 + e] + atomicAdd(&ctrl[8 + e], 1);
        row_token[p] = t;
        row_w[p] = tok_w[2*t + k];
        slot[2*t + k] = p;
    }
}

// ---------- K4: BK Green diag via Mobius prefix scan ----------
__global__ __launch_bounds__(256) void bk_scan_kernel(const float* __restrict__ v, float* __restrict__ feats) {
    int b = blockIdx.x;
    int t = threadIdx.x;
    __shared__ float sm[256][8];
    const mob I = {{1.f,0.f},{0.f,0.f},{0.f,0.f},{1.f,0.f}};
    cplx a[8];
    const float* vb = v + (size_t)b * NN;
    #pragma unroll
    for (int j = 0; j < 8; j++) { a[j].x = -2.f + vb[t*8 + j]; a[j].y = -1.f; }

    // forward: prefix products M_i ... M_0
    mob cur = I;
    #pragma unroll
    for (int j = 0; j < 8; j++) cur = mstep(a[j], cur);
    mnorm(cur);
    mstore(sm[t], cur);
    for (int s = 1; s < 256; s <<= 1) {
        __syncthreads();
        mob prev; bool has = (t >= s);
        if (has) prev = mload(sm[t - s]);
        __syncthreads();
        if (has) { cur = mmul(cur, prev); mnorm(cur); mstore(sm[t], cur); }
    }
    __syncthreads();
    mob P = (t > 0) ? mload(sm[t - 1]) : I;
    cplx dreg[8];
    #pragma unroll
    for (int j = 0; j < 8; j++) {
        P = mstep(a[j], P); mnorm(P);
        dreg[j] = cdivc(P.m00, P.m10);
    }
    __syncthreads();   // done reading sm from forward pass

    // backward: suffix products M_i ... M_{N-1}
    cur = I;
    #pragma unroll
    for (int j = 7; j >= 0; j--) cur = mstep(a[j], cur);
    mnorm(cur);
    mstore(sm[t], cur);
    for (int s = 1; s < 256; s <<= 1) {
        __syncthreads();
        mob nxt; bool has = (t + s < 256);
        if (has) nxt = mload(sm[t + s]);
        __syncthreads();
        if (has) { cur = mmul(cur, nxt); mnorm(cur); mstore(sm[t], cur); }
    }
    __syncthreads();
    P = (t < 255) ? mload(sm[t + 1]) : I;
    #pragma unroll
    for (int j = 7; j >= 0; j--) {
        P = mstep(a[j], P); mnorm(P);
        cplx e = cdivc(P.m00, P.m10);
        cplx den = {dreg[j].x + e.x - a[j].x, dreg[j].y + e.y - a[j].y};
        cplx one = {1.f, 0.f};
        cplx G = cdivc(one, den);
        int i = b * NN + t*8 + j;
        feats[2*i]   = G.x;
        feats[2*i+1] = G.y;
    }
}

// ---------- K5: GEMM1  H = gelu(Xg @ w1[e] + b1[e])  (bf16 staged inputs) ----------
__global__ __launch_bounds__(256) void gemm1_kernel(
    const ushort* __restrict__ x_bf, const ushort* __restrict__ w1_bf, const float* __restrict__ b1,
    const int* __restrict__ ctrl, const int* __restrict__ row_token, ushort* __restrict__ H)
{
    int tile = blockIdx.x;
    int e = ctrl[24 + tile];
    if (e < 0) return;
    int p0 = tile * 128;
    int f0 = blockIdx.y * 128;

    __shared__ ushort As[128 * LDST];
    __shared__ ushort Bs[128 * LDST];
    __shared__ int toks[128];

    int tid = threadIdx.x;
    if (tid < 128) toks[tid] = row_token[p0 + tid];

    floatx4 zero4 = {0.f, 0.f, 0.f, 0.f};
    floatx4 acc[4][4];
    #pragma unroll
    for (int i = 0; i < 4; i++)
        #pragma unroll
        for (int j = 0; j < 4; j++) acc[i][j] = zero4;

    int wave = tid >> 6, lane = tid & 63;
    int wm = (wave & 1) * 64, wn = (wave >> 1) * 64;
    int lm = lane & 15, q = lane >> 4;
    const ushort* w1e = w1_bf + (size_t)e * (DD * FF);
    int ar = tid >> 1, ac = (tid & 1) * 16;
    int bk = tid >> 3, bf = (tid & 7) * 16;
    __syncthreads();

    for (int k0 = 0; k0 < DD; k0 += 32) {
        // stage A (gathered token rows)
        int tok = toks[ar];
        uint4 a0 = make_uint4(0,0,0,0), a1 = make_uint4(0,0,0,0);
        if (tok >= 0) {
            const uint4* src = (const uint4*)(x_bf + (size_t)tok * DD + k0 + ac);
            a0 = src[0]; a1 = src[1];
        }
        *(uint4*)(As + ar * LDST + ac)     = a0;
        *(uint4*)(As + ar * LDST + ac + 8) = a1;
        // stage B transposed: Bs[f_local][k_local]
        {
            const ushort* bsrc = w1e + (size_t)(k0 + bk) * FF + f0 + bf;
            uint4 b0v = *(const uint4*)bsrc;
            uint4 b1v = *(const uint4*)(bsrc + 8);
            __align__(16) ushort tmp[16];
            *(uint4*)tmp = b0v; *(uint4*)(tmp + 8) = b1v;
            #pragma unroll
            for (int u = 0; u < 16; u++) Bs[(bf + u) * LDST + bk] = tmp[u];
        }
        __syncthreads();
        bf16x8 afr[4], bfr[4];
        #pragma unroll
        for (int i = 0; i < 4; i++)
            afr[i] = *(const bf16x8*)(const void*)(As + (wm + i*16 + lm) * LDST + q*8);
        #pragma unroll
        for (int j = 0; j < 4; j++)
            bfr[j] = *(const bf16x8*)(const void*)(Bs + (wn + j*16 + lm) * LDST + q*8);
        #pragma unroll
        for (int i = 0; i < 4; i++)
            #pragma unroll
            for (int j = 0; j < 4; j++)
                acc[i][j] = __builtin_amdgcn_mfma_f32_16x16x32_bf16(afr[i], bfr[j], acc[i][j], 0, 0, 0);
        __syncthreads();
    }
    // epilogue: bias + gelu, store bf16
    #pragma unroll
    for (int i = 0; i < 4; i++) {
        #pragma unroll
        for (int j = 0; j < 4; j++) {
            int n = wn + j*16 + lm;
            float bias = b1[e * FF + f0 + n];
            #pragma unroll
            for (int r = 0; r < 4; r++) {
                int m = wm + i*16 + q*4 + r;
                float hv = gelu_f(acc[i][j][r] + bias);
                H[(size_t)(p0 + m) * FF + f0 + n] = f2b(hv);
            }
        }
    }
}

// ---------- K6: GEMM2  Y = row_w * (H @ w2[e] + b2[e]) ----------
__global__ __launch_bounds__(256) void gemm2_kernel(
    const ushort* __restrict__ H, const ushort* __restrict__ w2_bf, const float* __restrict__ b2,
    const int* __restrict__ ctrl, const float* __restrict__ row_w, float* __restrict__ Y)
{
    int tile = blockIdx.x;
    int e = ctrl[24 + tile];
    if (e < 0) return;
    int p0 = tile * 128;
    int d0 = blockIdx.y * 128;

    __shared__ ushort As[128 * LDST];
    __shared__ ushort Bs[128 * LDST];

    int tid = threadIdx.x;
    floatx4 zero4 = {0.f, 0.f, 0.f, 0.f};
    floatx4 acc[4][4];
    #pragma unroll
    for (int i = 0; i < 4; i++)
        #pragma unroll
        for (int j = 0; j < 4; j++) acc[i][j] = zero4;

    int wave = tid >> 6, lane = tid & 63;
    int wm = (wave & 1) * 64, wn = (wave >> 1) * 64;
    int lm = lane & 15, q = lane >> 4;
    const ushort* w2e = w2_bf + (size_t)e * (FF * DD);
    int ar = tid >> 1, ac = (tid & 1) * 16;
    int bk = tid >> 3, bf = (tid & 7) * 16;

    for (int k0 = 0; k0 < FF; k0 += 32) {
        const uint4* src = (const uint4*)(H + (size_t)(p0 + ar) * FF + k0 + ac);
        uint4 a0 = src[0], a1 = src[1];
        *(uint4*)(As + ar * LDST + ac)     = a0;
        *(uint4*)(As + ar * LDST + ac + 8) = a1;
        {
            const ushort* bsrc = w2e + (size_t)(k0 + bk) * DD + d0 + bf;
            uint4 b0v = *(const uint4*)bsrc;
            uint4 b1v = *(const uint4*)(bsrc + 8);
            __align__(16) ushort tmp[16];
            *(uint4*)tmp = b0v; *(uint4*)(tmp + 8) = b1v;
            #pragma unroll
            for (int u = 0; u < 16; u++) Bs[(bf + u) * LDST + bk] = tmp[u];
        }
        __syncthreads();
        bf16x8 afr[4], bfr[4];
        #pragma unroll
        for (int i = 0; i < 4; i++)
            afr[i] = *(const bf16x8*)(const void*)(As + (wm + i*16 + lm) * LDST + q*8);
        #pragma unroll
        for (int j = 0; j < 4; j++)
            bfr[j] = *(const bf16x8*)(const void*)(Bs + (wn + j*16 + lm) * LDST + q*8);
        #pragma unroll
        for (int i = 0; i < 4; i++)
            #pragma unroll
            for (int j = 0; j < 4; j++)
                acc[i][j] = __builtin_amdgcn_mfma_f32_16x16x32_bf16(afr[i], bfr[j], acc[i][j], 0, 0, 0);
        __syncthreads();
    }
    #pragma unroll
    for (int i = 0; i < 4; i++) {
        #pragma unroll
        for (int j = 0; j < 4; j++) {
            int n = wn + j*16 + lm;
            float bias = b2[e * DD + d0 + n];
            #pragma unroll
            for (int r = 0; r < 4; r++) {
                int m = wm + i*16 + q*4 + r;
                float wgt = row_w[p0 + m];
                Y[(size_t)(p0 + m) * DD + d0 + n] = wgt * (acc[i][j][r] + bias);
            }
        }
    }
}

// ---------- K7: final combine (fp32 out) ----------
__global__ __launch_bounds__(256) void final_kernel(
    const float* __restrict__ Y, const int* __restrict__ slot, const float* __restrict__ feats,
    const float* __restrict__ out_w, const float* __restrict__ out_b,
    const float* __restrict__ bk_scale, float* __restrict__ out)
{
    int idx = blockIdx.x * 256 + threadIdx.x;
    int base = idx * 4;
    int t = base / DD;
    int d = base - t * DD;
    int p0 = slot[2*t], p1 = slot[2*t + 1];
    const float4 ya = *(const float4*)(Y + (size_t)p0 * DD + d);
    const float4 yb = *(const float4*)(Y + (size_t)p1 * DD + d);
    float f0 = feats[2*t], f1 = feats[2*t + 1];
    f0 = fminf(fmaxf(f0, -10.f), 10.f);
    f1 = fminf(fmaxf(f1, -10.f), 10.f);
    float ff[4] = {ya.x + yb.x, ya.y + yb.y, ya.z + yb.z, ya.w + yb.w};
    float4 o;
    float* op = (float*)&o;
    #pragma unroll
    for (int u = 0; u < 4; u++) {
        float spec = f0 * out_w[d + u] + f1 * out_w[DD + d + u] + out_b[d + u];
        op[u] = ff[u] + bk_scale[d + u] * spec;
    }
    *(float4*)(out + base) = o;
}

extern "C" void kernel_launch(void* const* d_in, const int* in_sizes, int n_in,
                              void* d_out, int out_size, void* d_ws, size_t ws_size,
                              hipStream_t stream)
{
    const float* x      = (const float*)d_in[0];
    const float* v_w    = (const float*)d_in[1];
    const float* v_b    = (const float*)d_in[2];
    const float* gate_w = (const float*)d_in[3];
    const float* gate_b = (const float*)d_in[4];
    const float* w1     = (const float*)d_in[5];
    const float* b1     = (const float*)d_in[6];
    const float* w2     = (const float*)d_in[7];
    const float* b2     = (const float*)d_in[8];
    const float* out_w  = (const float*)d_in[9];
    const float* out_b  = (const float*)d_in[10];
    const float* bk_s   = (const float*)d_in[11];

    char* ws = (char*)d_ws;
    int*    ctrl    = (int*)(ws + OFF_CTRL);
    float*  v       = (float*)(ws + OFF_V);
    int*    tok_e   = (int*)(ws + OFF_TOKE);
    float*  tok_w   = (float*)(ws + OFF_TOKW);
    int*    row_tok = (int*)(ws + OFF_ROWTOK);
    float*  row_w   = (float*)(ws + OFF_ROWW);
    int*    slot    = (int*)(ws + OFF_SLOT);
    float*  feats   = (float*)(ws + OFF_FEATS);
    ushort* w2_bf   = (ushort*)(ws + OFF_W2BF);
    ushort* x_bf    = (ushort*)(ws + OFF_XBF);
    ushort* w1_bf   = (ushort*)(ws + OFF_W1BF);
    ushort* H       = (ushort*)(ws + OFF_H);
    float*  Y       = (float*)(ws + OFF_Y);
    float*  out     = (float*)d_out;

    zero_ctrl_kernel<<<1, 64, 0, stream>>>(ctrl);
    cvt_kernel<<<(TOK*DD)/8/256, 256, 0, stream>>>(x, x_bf, (TOK*DD)/8);
    cvt_kernel<<<(EE*DD*FF)/8/256, 256, 0, stream>>>(w1, w1_bf, (EE*DD*FF)/8);
    cvt_kernel<<<(EE*FF*DD)/8/256, 256, 0, stream>>>(w2, w2_bf, (EE*FF*DD)/8);
    routing_kernel<<<TOK / 4, 256, 0, stream>>>(x, v_w, v_b, gate_w, gate_b, v, tok_e, tok_w, ctrl);
    setup_kernel<<<1, 256, 0, stream>>>(ctrl, row_tok);
    scatter_kernel<<<TOK / 256, 256, 0, stream>>>(tok_e, tok_w, ctrl, row_tok, row_w, slot);
    bk_scan_kernel<<<BB, 256, 0, stream>>>(v, feats);
    gemm1_kernel<<<dim3(TILES, FF / 128), 256, 0, stream>>>(x_bf, w1_bf, b1, ctrl, row_tok, H);
    gemm2_kernel<<<dim3(TILES, DD / 128), 256, 0, stream>>>(H, w2_bf, b2, ctrl, row_w, Y);
    final_kernel<<<(TOK * DD) / 1024, 256, 0, stream>>>(Y, slot, feats, out_w, out_b, bk_s, out);
}

// Round 3
// 522.999 us; speedup vs baseline: 1.2255x; 1.2255x over previous
//
#include <hip/hip_runtime.h>
#include <hip/hip_bf16.h>

#define BB 2
#define NN 2048
#define DD 768
#define EE 8
#define FF 3072
#define TOK (BB*NN)       // 4096
#define ROWS_CAP 9216     // 8192 slots + 8*128 alignment pad
#define TILES 72          // ROWS_CAP / 128

typedef __attribute__((ext_vector_type(8))) __bf16 bf16x8;
typedef __attribute__((ext_vector_type(4))) float floatx4;

// ---------- ws layout (bytes) ----------
#define OFF_CTRL    0ull                    // int[96]: cnt@0, cursor@8, base@16, tile_expert@24
#define OFF_V       1024ull                 // float[4096]
#define OFF_TOKE    17408ull                // int[8192]
#define OFF_TOKW    50176ull                // float[8192]
#define OFF_ROWTOK  82944ull                // int[9216]
#define OFF_ROWW    119808ull               // float[9216]
#define OFF_SLOT    156672ull               // int[8192]
#define OFF_FEATS   189440ull               // float[8192]
// big buffers
#define OFF_W2T     222208ull               // ushort[8*768*3072] = 37,748,736 B   (w2^T: [e][d][f])
#define OFF_XBF     37970944ull             // ushort[4096*768]   = 6,291,456 B
#define OFF_W1T     44262400ull             // ushort[8*3072*768] = 37,748,736 B   (w1^T: [e][f][d])
#define OFF_H       82011136ull             // ushort[9216*3072]  = 56,623,104 B -> end 138,634,240
#define OFF_Y       OFF_XBF                 // float[9216*768] = 28,311,552 B, aliases dead XBF+W1T

__device__ __forceinline__ ushort f2b(float f) {
    union { float f; unsigned int i; } v; v.f = f;
    unsigned int u = v.i;
    unsigned int r = (u + 0x7FFFu + ((u >> 16) & 1u)) >> 16;
    return (ushort)r;
}
__device__ __forceinline__ unsigned int pk2(float lo, float hi) {
    union { float f; unsigned int u; } a, b;
    a.f = lo; b.f = hi;
    unsigned int ra = ((a.u + 0x7FFFu + ((a.u >> 16) & 1u)) >> 16) & 0xFFFFu;
    unsigned int rb = (b.u + 0x7FFFu + ((b.u >> 16) & 1u)) & 0xFFFF0000u;
    return ra | rb;
}
__device__ __forceinline__ float gelu_f(float x) {
    float z = 0.7978845608028654f * x * (1.f + 0.044715f * x * x);
    z = fminf(fmaxf(z, -12.f), 12.f);
    float e = __expf(2.f * z);
    return 0.5f * x * (1.f + (e - 1.f) / (e + 1.f));
}
// async global(16B/lane) -> LDS (wave-uniform base + lane*16)
__device__ __forceinline__ void gload16(const ushort* g, ushort* l) {
    __builtin_amdgcn_global_load_lds((const __attribute__((address_space(1))) void*)g,
                                     (__attribute__((address_space(3))) void*)l,
                                     16, 0, 0);
}

// ---------- complex / Mobius helpers ----------
struct cplx { float x, y; };
__device__ __forceinline__ cplx cmulc(cplx a, cplx b) { return {a.x*b.x - a.y*b.y, a.x*b.y + a.y*b.x}; }
__device__ __forceinline__ cplx caddc(cplx a, cplx b) { return {a.x + b.x, a.y + b.y}; }
__device__ __forceinline__ cplx cdivc(cplx a, cplx b) {
    float s = 1.f / (b.x*b.x + b.y*b.y);
    return {(a.x*b.x + a.y*b.y)*s, (a.y*b.x - a.x*b.y)*s};
}
struct mob { cplx m00, m01, m10, m11; };
__device__ __forceinline__ mob mmul(const mob& A, const mob& B) {
    mob C;
    C.m00 = caddc(cmulc(A.m00, B.m00), cmulc(A.m01, B.m10));
    C.m01 = caddc(cmulc(A.m00, B.m01), cmulc(A.m01, B.m11));
    C.m10 = caddc(cmulc(A.m10, B.m00), cmulc(A.m11, B.m10));
    C.m11 = caddc(cmulc(A.m10, B.m01), cmulc(A.m11, B.m11));
    return C;
}
__device__ __forceinline__ void mnorm(mob& A) {
    float s = fabsf(A.m00.x);
    s = fmaxf(s, fabsf(A.m00.y)); s = fmaxf(s, fabsf(A.m01.x)); s = fmaxf(s, fabsf(A.m01.y));
    s = fmaxf(s, fabsf(A.m10.x)); s = fmaxf(s, fabsf(A.m10.y)); s = fmaxf(s, fabsf(A.m11.x));
    s = fmaxf(s, fabsf(A.m11.y));
    float r = 1.f / fmaxf(s, 1e-30f);
    A.m00.x *= r; A.m00.y *= r; A.m01.x *= r; A.m01.y *= r;
    A.m10.x *= r; A.m10.y *= r; A.m11.x *= r; A.m11.y *= r;
}
__device__ __forceinline__ mob mstep(cplx a, const mob& P) {
    mob C;
    C.m00 = {a.x*P.m00.x - a.y*P.m00.y - P.m10.x, a.x*P.m00.y + a.y*P.m00.x - P.m10.y};
    C.m01 = {a.x*P.m01.x - a.y*P.m01.y - P.m11.x, a.x*P.m01.y + a.y*P.m01.x - P.m11.y};
    C.m10 = P.m00; C.m11 = P.m01;
    return C;
}
__device__ __forceinline__ void mstore(float* s, const mob& A) {
    s[0]=A.m00.x; s[1]=A.m00.y; s[2]=A.m01.x; s[3]=A.m01.y;
    s[4]=A.m10.x; s[5]=A.m10.y; s[6]=A.m11.x; s[7]=A.m11.y;
}
__device__ __forceinline__ mob mload(const float* s) {
    mob A;
    A.m00 = {s[0], s[1]}; A.m01 = {s[2], s[3]};
    A.m10 = {s[4], s[5]}; A.m11 = {s[6], s[7]};
    return A;
}

// ---------- K0: zero control ----------
__global__ void zero_ctrl_kernel(int* ctrl) {
    int tid = threadIdx.x;
    if (tid < 16) ctrl[tid] = 0;
}

// ---------- K0b: fp32 -> bf16 bulk convert (8 elems/thread) ----------
__global__ __launch_bounds__(256) void cvt_kernel(
    const float* __restrict__ src, ushort* __restrict__ dst, int n8)
{
    int i = blockIdx.x * 256 + threadIdx.x;
    if (i >= n8) return;
    const float4* s = ((const float4*)src) + (size_t)i * 2;
    float4 a = s[0], b = s[1];
    uint4 o;
    o.x = pk2(a.x, a.y); o.y = pk2(a.z, a.w);
    o.z = pk2(b.x, b.y); o.w = pk2(b.z, b.w);
    *(((uint4*)dst) + i) = o;
}

// ---------- K0c: fp32 [R][C] -> bf16 transposed [C][R], per-expert (blockIdx.z) ----------
__global__ __launch_bounds__(256) void tcvt_kernel(
    const float* __restrict__ src, ushort* __restrict__ dst, int R, int C)
{
    size_t eoff = (size_t)blockIdx.z * R * C;
    const float* s = src + eoff;
    ushort* d = dst + eoff;
    __shared__ float t[32][33];
    int c0 = blockIdx.x * 32, r0 = blockIdx.y * 32;
    int tid = threadIdx.x;
    int tr = tid >> 3, tc = (tid & 7) * 4;
    float4 vsrc = *(const float4*)(s + (size_t)(r0 + tr) * C + c0 + tc);
    t[tr][tc] = vsrc.x; t[tr][tc+1] = vsrc.y; t[tr][tc+2] = vsrc.z; t[tr][tc+3] = vsrc.w;
    __syncthreads();
    ushort4 o;
    o.x = f2b(t[tc  ][tr]);
    o.y = f2b(t[tc+1][tr]);
    o.z = f2b(t[tc+2][tr]);
    o.w = f2b(t[tc+3][tr]);
    *(ushort4*)(d + (size_t)(c0 + tr) * R + r0 + tc) = o;
}

// ---------- K1: routing (one wave per token), fp32 inputs ----------
__global__ __launch_bounds__(256) void routing_kernel(
    const float* __restrict__ x, const float* __restrict__ v_w, const float* __restrict__ v_b,
    const float* __restrict__ gate_w, const float* __restrict__ gate_b,
    float* __restrict__ v_out, int* __restrict__ tok_e, float* __restrict__ tok_w,
    int* __restrict__ ctrl)
{
    int wave = threadIdx.x >> 6, lane = threadIdx.x & 63;
    int t = blockIdx.x * 4 + wave;
    const float* xr = x + (size_t)t * DD;
    float av = 0.f;
    float ag[8] = {0.f, 0.f, 0.f, 0.f, 0.f, 0.f, 0.f, 0.f};
    #pragma unroll
    for (int i = 0; i < 12; i++) {
        int d = lane + 64 * i;
        float xv = xr[d];
        av += xv * v_w[d];
        const float4* g = (const float4*)(gate_w + d * 8);
        float4 g0 = g[0], g1 = g[1];
        ag[0] += xv * g0.x; ag[1] += xv * g0.y; ag[2] += xv * g0.z; ag[3] += xv * g0.w;
        ag[4] += xv * g1.x; ag[5] += xv * g1.y; ag[6] += xv * g1.z; ag[7] += xv * g1.w;
    }
    #pragma unroll
    for (int off = 32; off >= 1; off >>= 1) {
        av += __shfl_xor(av, off);
        #pragma unroll
        for (int e = 0; e < 8; e++) ag[e] += __shfl_xor(ag[e], off);
    }
    if (lane == 0) {
        float vv = av + v_b[0];
        vv = fminf(fmaxf(vv, -3.f), 3.f);
        v_out[t] = vv;
        float lg[8];
        #pragma unroll
        for (int e = 0; e < 8; e++) lg[e] = ag[e] + gate_b[e];
        int e0 = 0;
        #pragma unroll
        for (int e = 1; e < 8; e++) if (lg[e] > lg[e0]) e0 = e;
        int e1 = -1;
        #pragma unroll
        for (int e = 0; e < 8; e++) if (e != e0 && (e1 < 0 || lg[e] > lg[e1])) e1 = e;
        float w0 = 1.f / (1.f + __expf(lg[e1] - lg[e0]));
        tok_e[2*t] = e0; tok_e[2*t+1] = e1;
        tok_w[2*t] = w0; tok_w[2*t+1] = 1.f - w0;
        atomicAdd(&ctrl[e0], 1);
        atomicAdd(&ctrl[e1], 1);
    }
}

// ---------- K2: bases, tile map, row_token init ----------
__global__ void setup_kernel(int* __restrict__ ctrl, int* __restrict__ row_token) {
    int tid = threadIdx.x;
    if (tid == 0) {
        int* cnt  = ctrl;
        int* base = ctrl + 16;
        int* te   = ctrl + 24;
        for (int i = 0; i < TILES; i++) te[i] = -1;
        int b = 0;
        for (int e = 0; e < EE; e++) {
            base[e] = b;
            int tiles = (cnt[e] + 127) >> 7;
            int t0 = b >> 7;
            for (int i = 0; i < tiles; i++) te[t0 + i] = e;
            b += tiles << 7;
        }
    }
    for (int p = tid; p < ROWS_CAP; p += 256) row_token[p] = -1;
}

// ---------- K3: scatter tokens into expert rows ----------
__global__ __launch_bounds__(256) void scatter_kernel(
    const int* __restrict__ tok_e, const float* __restrict__ tok_w,
    int* __restrict__ ctrl, int* __restrict__ row_token, float* __restrict__ row_w,
    int* __restrict__ slot)
{
    int t = blockIdx.x * 256 + threadIdx.x;
    #pragma unroll
    for (int k = 0; k < 2; k++) {
        int e = tok_e[2*t + k];
        int p = ctrl[16 + e] + atomicAdd(&ctrl[8 + e], 1);
        row_token[p] = t;
        row_w[p] = tok_w[2*t + k];
        slot[2*t + k] = p;
    }
}

// ---------- K4: BK Green diag via Mobius prefix scan ----------
__global__ __launch_bounds__(256) void bk_scan_kernel(const float* __restrict__ v, float* __restrict__ feats) {
    int b = blockIdx.x;
    int t = threadIdx.x;
    __shared__ float sm[256][8];
    const mob I = {{1.f,0.f},{0.f,0.f},{0.f,0.f},{1.f,0.f}};
    cplx a[8];
    const float* vb = v + (size_t)b * NN;
    #pragma unroll
    for (int j = 0; j < 8; j++) { a[j].x = -2.f + vb[t*8 + j]; a[j].y = -1.f; }

    mob cur = I;
    #pragma unroll
    for (int j = 0; j < 8; j++) cur = mstep(a[j], cur);
    mnorm(cur);
    mstore(sm[t], cur);
    for (int s = 1; s < 256; s <<= 1) {
        __syncthreads();
        mob prev; bool has = (t >= s);
        if (has) prev = mload(sm[t - s]);
        __syncthreads();
        if (has) { cur = mmul(cur, prev); mnorm(cur); mstore(sm[t], cur); }
    }
    __syncthreads();
    mob P = (t > 0) ? mload(sm[t - 1]) : I;
    cplx dreg[8];
    #pragma unroll
    for (int j = 0; j < 8; j++) {
        P = mstep(a[j], P); mnorm(P);
        dreg[j] = cdivc(P.m00, P.m10);
    }
    __syncthreads();

    cur = I;
    #pragma unroll
    for (int j = 7; j >= 0; j--) cur = mstep(a[j], cur);
    mnorm(cur);
    mstore(sm[t], cur);
    for (int s = 1; s < 256; s <<= 1) {
        __syncthreads();
        mob nxt; bool has = (t + s < 256);
        if (has) nxt = mload(sm[t + s]);
        __syncthreads();
        if (has) { cur = mmul(cur, nxt); mnorm(cur); mstore(sm[t], cur); }
    }
    __syncthreads();
    P = (t < 255) ? mload(sm[t + 1]) : I;
    #pragma unroll
    for (int j = 7; j >= 0; j--) {
        P = mstep(a[j], P); mnorm(P);
        cplx e = cdivc(P.m00, P.m10);
        cplx den = {dreg[j].x + e.x - a[j].x, dreg[j].y + e.y - a[j].y};
        cplx one = {1.f, 0.f};
        cplx G = cdivc(one, den);
        int i = b * NN + t*8 + j;
        feats[2*i]   = G.x;
        feats[2*i+1] = G.y;
    }
}

// ---------- K5: GEMM1  H = gelu(Xg @ w1t[e]^T + b1[e])  — both operands K-major ----------
__global__ __launch_bounds__(256) void gemm1_kernel(
    const ushort* __restrict__ x_bf, const ushort* __restrict__ w1t, const float* __restrict__ b1,
    const int* __restrict__ ctrl, const int* __restrict__ row_token, ushort* __restrict__ H)
{
    int tile = blockIdx.x;
    int e = ctrl[24 + tile];
    if (e < 0) return;
    int p0 = tile * 128;
    int f0 = blockIdx.y * 128;

    __shared__ ushort As[128 * 32];
    __shared__ ushort Bs[128 * 32];
    __shared__ int toks[128];

    int tid = threadIdx.x;
    if (tid < 128) { int tk = row_token[p0 + tid]; toks[tid] = tk < 0 ? 0 : tk; }
    __syncthreads();

    int wave = tid >> 6, lane = tid & 63;
    int rsub = lane >> 2;            // row within 16-row issue
    int kq = (lane & 3) * 8;         // k offset (ushorts)
    int tokA0 = toks[wave*32 + rsub];
    int tokA1 = toks[wave*32 + 16 + rsub];
    const ushort* aglob0 = x_bf + (size_t)tokA0 * DD + kq;
    const ushort* aglob1 = x_bf + (size_t)tokA1 * DD + kq;
    const ushort* w1e = w1t + (size_t)e * (FF * DD);      // [f][d] row stride DD
    const ushort* bglob0 = w1e + (size_t)(f0 + wave*32 + rsub) * DD + kq;
    const ushort* bglob1 = bglob0 + (size_t)16 * DD;
    ushort* AsW = As + wave * 32 * 32;
    ushort* BsW = Bs + wave * 32 * 32;

    floatx4 zero4 = {0.f, 0.f, 0.f, 0.f};
    floatx4 acc[4][4];
    #pragma unroll
    for (int i = 0; i < 4; i++)
        #pragma unroll
        for (int j = 0; j < 4; j++) acc[i][j] = zero4;

    int wm = (wave & 1) * 64, wn = (wave >> 1) * 64;
    int lm = lane & 15, q = lane >> 4;

    for (int k0 = 0; k0 < DD; k0 += 32) {
        gload16(aglob0 + k0, AsW);
        gload16(aglob1 + k0, AsW + 16*32);
        gload16(bglob0 + k0, BsW);
        gload16(bglob1 + k0, BsW + 16*32);
        __syncthreads();
        bf16x8 afr[4], bfr[4];
        #pragma unroll
        for (int i = 0; i < 4; i++)
            afr[i] = *(const bf16x8*)(const void*)(As + (wm + i*16 + lm) * 32 + q*8);
        #pragma unroll
        for (int j = 0; j < 4; j++)
            bfr[j] = *(const bf16x8*)(const void*)(Bs + (wn + j*16 + lm) * 32 + q*8);
        #pragma unroll
        for (int i = 0; i < 4; i++)
            #pragma unroll
            for (int j = 0; j < 4; j++)
                acc[i][j] = __builtin_amdgcn_mfma_f32_16x16x32_bf16(afr[i], bfr[j], acc[i][j], 0, 0, 0);
        __syncthreads();
    }
    #pragma unroll
    for (int i = 0; i < 4; i++) {
        #pragma unroll
        for (int j = 0; j < 4; j++) {
            int n = wn + j*16 + lm;
            float bias = b1[e * FF + f0 + n];
            #pragma unroll
            for (int r = 0; r < 4; r++) {
                int m = wm + i*16 + q*4 + r;
                float hv = gelu_f(acc[i][j][r] + bias);
                H[(size_t)(p0 + m) * FF + f0 + n] = f2b(hv);
            }
        }
    }
}

// ---------- K6: GEMM2  Y = row_w * (H @ w2t[e]^T + b2[e]) ----------
__global__ __launch_bounds__(256) void gemm2_kernel(
    const ushort* __restrict__ H, const ushort* __restrict__ w2t, const float* __restrict__ b2,
    const int* __restrict__ ctrl, const float* __restrict__ row_w, float* __restrict__ Y)
{
    int tile = blockIdx.x;
    int e = ctrl[24 + tile];
    if (e < 0) return;
    int p0 = tile * 128;
    int d0 = blockIdx.y * 128;

    __shared__ ushort As[128 * 32];
    __shared__ ushort Bs[128 * 32];

    int tid = threadIdx.x;
    int wave = tid >> 6, lane = tid & 63;
    int rsub = lane >> 2;
    int kq = (lane & 3) * 8;
    const ushort* aglob0 = H + (size_t)(p0 + wave*32 + rsub) * FF + kq;
    const ushort* aglob1 = aglob0 + (size_t)16 * FF;
    const ushort* w2e = w2t + (size_t)e * (DD * FF);      // [d][f] row stride FF
    const ushort* bglob0 = w2e + (size_t)(d0 + wave*32 + rsub) * FF + kq;
    const ushort* bglob1 = bglob0 + (size_t)16 * FF;
    ushort* AsW = As + wave * 32 * 32;
    ushort* BsW = Bs + wave * 32 * 32;

    floatx4 zero4 = {0.f, 0.f, 0.f, 0.f};
    floatx4 acc[4][4];
    #pragma unroll
    for (int i = 0; i < 4; i++)
        #pragma unroll
        for (int j = 0; j < 4; j++) acc[i][j] = zero4;

    int wm = (wave & 1) * 64, wn = (wave >> 1) * 64;
    int lm = lane & 15, q = lane >> 4;

    for (int k0 = 0; k0 < FF; k0 += 32) {
        gload16(aglob0 + k0, AsW);
        gload16(aglob1 + k0, AsW + 16*32);
        gload16(bglob0 + k0, BsW);
        gload16(bglob1 + k0, BsW + 16*32);
        __syncthreads();
        bf16x8 afr[4], bfr[4];
        #pragma unroll
        for (int i = 0; i < 4; i++)
            afr[i] = *(const bf16x8*)(const void*)(As + (wm + i*16 + lm) * 32 + q*8);
        #pragma unroll
        for (int j = 0; j < 4; j++)
            bfr[j] = *(const bf16x8*)(const void*)(Bs + (wn + j*16 + lm) * 32 + q*8);
        #pragma unroll
        for (int i = 0; i < 4; i++)
            #pragma unroll
            for (int j = 0; j < 4; j++)
                acc[i][j] = __builtin_amdgcn_mfma_f32_16x16x32_bf16(afr[i], bfr[j], acc[i][j], 0, 0, 0);
        __syncthreads();
    }
    #pragma unroll
    for (int i = 0; i < 4; i++) {
        #pragma unroll
        for (int j = 0; j < 4; j++) {
            int n = wn + j*16 + lm;
            float bias = b2[e * DD + d0 + n];
            #pragma unroll
            for (int r = 0; r < 4; r++) {
                int m = wm + i*16 + q*4 + r;
                float wgt = row_w[p0 + m];
                Y[(size_t)(p0 + m) * DD + d0 + n] = wgt * (acc[i][j][r] + bias);
            }
        }
    }
}

// ---------- K7: final combine (fp32 out) ----------
__global__ __launch_bounds__(256) void final_kernel(
    const float* __restrict__ Y, const int* __restrict__ slot, const float* __restrict__ feats,
    const float* __restrict__ out_w, const float* __restrict__ out_b,
    const float* __restrict__ bk_scale, float* __restrict__ out)
{
    int idx = blockIdx.x * 256 + threadIdx.x;
    int base = idx * 4;
    int t = base / DD;
    int d = base - t * DD;
    int p0 = slot[2*t], p1 = slot[2*t + 1];
    const float4 ya = *(const float4*)(Y + (size_t)p0 * DD + d);
    const float4 yb = *(const float4*)(Y + (size_t)p1 * DD + d);
    float f0 = feats[2*t], f1 = feats[2*t + 1];
    f0 = fminf(fmaxf(f0, -10.f), 10.f);
    f1 = fminf(fmaxf(f1, -10.f), 10.f);
    float ff[4] = {ya.x + yb.x, ya.y + yb.y, ya.z + yb.z, ya.w + yb.w};
    float4 o;
    float* op = (float*)&o;
    #pragma unroll
    for (int u = 0; u < 4; u++) {
        float spec = f0 * out_w[d + u] + f1 * out_w[DD + d + u] + out_b[d + u];
        op[u] = ff[u] + bk_scale[d + u] * spec;
    }
    *(float4*)(out + base) = o;
}

extern "C" void kernel_launch(void* const* d_in, const int* in_sizes, int n_in,
                              void* d_out, int out_size, void* d_ws, size_t ws_size,
                              hipStream_t stream)
{
    const float* x      = (const float*)d_in[0];
    const float* v_w    = (const float*)d_in[1];
    const float* v_b    = (const float*)d_in[2];
    const float* gate_w = (const float*)d_in[3];
    const float* gate_b = (const float*)d_in[4];
    const float* w1     = (const float*)d_in[5];
    const float* b1     = (const float*)d_in[6];
    const float* w2     = (const float*)d_in[7];
    const float* b2     = (const float*)d_in[8];
    const float* out_w  = (const float*)d_in[9];
    const float* out_b  = (const float*)d_in[10];
    const float* bk_s   = (const float*)d_in[11];

    char* ws = (char*)d_ws;
    int*    ctrl    = (int*)(ws + OFF_CTRL);
    float*  v       = (float*)(ws + OFF_V);
    int*    tok_e   = (int*)(ws + OFF_TOKE);
    float*  tok_w   = (float*)(ws + OFF_TOKW);
    int*    row_tok = (int*)(ws + OFF_ROWTOK);
    float*  row_w   = (float*)(ws + OFF_ROWW);
    int*    slot    = (int*)(ws + OFF_SLOT);
    float*  feats   = (float*)(ws + OFF_FEATS);
    ushort* w2t     = (ushort*)(ws + OFF_W2T);
    ushort* x_bf    = (ushort*)(ws + OFF_XBF);
    ushort* w1t     = (ushort*)(ws + OFF_W1T);
    ushort* H       = (ushort*)(ws + OFF_H);
    float*  Y       = (float*)(ws + OFF_Y);
    float*  out     = (float*)d_out;

    zero_ctrl_kernel<<<1, 64, 0, stream>>>(ctrl);
    cvt_kernel<<<(TOK*DD)/8/256, 256, 0, stream>>>(x, x_bf, (TOK*DD)/8);
    // w1: [e][768][3072] -> w1t [e][3072][768]
    tcvt_kernel<<<dim3(FF/32, DD/32, EE), 256, 0, stream>>>(w1, w1t, DD, FF);
    // w2: [e][3072][768] -> w2t [e][768][3072]
    tcvt_kernel<<<dim3(DD/32, FF/32, EE), 256, 0, stream>>>(w2, w2t, FF, DD);
    routing_kernel<<<TOK / 4, 256, 0, stream>>>(x, v_w, v_b, gate_w, gate_b, v, tok_e, tok_w, ctrl);
    setup_kernel<<<1, 256, 0, stream>>>(ctrl, row_tok);
    scatter_kernel<<<TOK / 256, 256, 0, stream>>>(tok_e, tok_w, ctrl, row_tok, row_w, slot);
    bk_scan_kernel<<<BB, 256, 0, stream>>>(v, feats);
    gemm1_kernel<<<dim3(TILES, FF / 128), 256, 0, stream>>>(x_bf, w1t, b1, ctrl, row_tok, H);
    gemm2_kernel<<<dim3(TILES, DD / 128), 256, 0, stream>>>(H, w2t, b2, ctrl, row_w, Y);
    final_kernel<<<(TOK * DD) / 1024, 256, 0, stream>>>(Y, slot, feats, out_w, out_b, bk_s, out);
}

// Round 4
// 411.597 us; speedup vs baseline: 1.5572x; 1.2707x over previous
//
#include <hip/hip_runtime.h>
#include <hip/hip_bf16.h>

#define BB 2
#define NN 2048
#define DD 768
#define EE 8
#define FF 3072
#define TOK (BB*NN)       // 4096
#define ROWS_CAP 9216     // 8192 slots + 8*128 alignment pad
#define TILES 72          // ROWS_CAP / 128

typedef __attribute__((ext_vector_type(8))) __bf16 bf16x8;
typedef __attribute__((ext_vector_type(4))) float floatx4;

// ---------- ws layout (bytes) ----------
#define OFF_CTRL    0ull                    // int[96]: base@16, tile_expert@24
#define OFF_V       1024ull                 // float[4096]
#define OFF_TOKE    17408ull                // int[8192]
#define OFF_TOKW    50176ull                // float[8192]
#define OFF_ROWTOK  82944ull                // int[9216]
#define OFF_ROWW    119808ull               // float[9216]
#define OFF_SLOT    156672ull               // int[8192]
#define OFF_FEATS   189440ull               // float[8192]
// big buffers
#define OFF_W2T     222208ull               // ushort[8*768*3072] = 37,748,736 B   (w2^T: [e][d][f])
#define OFF_XBF     37970944ull             // ushort[4096*768]   = 6,291,456 B
#define OFF_W1T     44262400ull             // ushort[8*3072*768] = 37,748,736 B   (w1^T: [e][f][d])
#define OFF_H       82011136ull             // ushort[9216*3072]  = 56,623,104 B -> end 138,634,240
#define OFF_Y       OFF_XBF                 // float[9216*768] = 28,311,552 B, aliases dead XBF+W1T

__device__ __forceinline__ ushort f2b(float f) {
    union { float f; unsigned int i; } v; v.f = f;
    unsigned int u = v.i;
    unsigned int r = (u + 0x7FFFu + ((u >> 16) & 1u)) >> 16;
    return (ushort)r;
}
__device__ __forceinline__ unsigned int pk2(float lo, float hi) {
    union { float f; unsigned int u; } a, b;
    a.f = lo; b.f = hi;
    unsigned int ra = ((a.u + 0x7FFFu + ((a.u >> 16) & 1u)) >> 16) & 0xFFFFu;
    unsigned int rb = (b.u + 0x7FFFu + ((b.u >> 16) & 1u)) & 0xFFFF0000u;
    return ra | rb;
}
__device__ __forceinline__ float gelu_f(float x) {
    float z = 0.7978845608028654f * x * (1.f + 0.044715f * x * x);
    z = fminf(fmaxf(z, -12.f), 12.f);
    float e = __expf(2.f * z);
    return 0.5f * x * (1.f + (e - 1.f) / (e + 1.f));
}
// async global(16B/lane) -> LDS (wave-uniform base + lane*16)
__device__ __forceinline__ void gload16(const ushort* g, ushort* l) {
    __builtin_amdgcn_global_load_lds((const __attribute__((address_space(1))) void*)g,
                                     (__attribute__((address_space(3))) void*)l,
                                     16, 0, 0);
}

// ---------- complex / Mobius helpers ----------
struct cplx { float x, y; };
__device__ __forceinline__ cplx cmulc(cplx a, cplx b) { return {a.x*b.x - a.y*b.y, a.x*b.y + a.y*b.x}; }
__device__ __forceinline__ cplx caddc(cplx a, cplx b) { return {a.x + b.x, a.y + b.y}; }
__device__ __forceinline__ cplx cdivc(cplx a, cplx b) {
    float s = 1.f / (b.x*b.x + b.y*b.y);
    return {(a.x*b.x + a.y*b.y)*s, (a.y*b.x - a.x*b.y)*s};
}
struct mob { cplx m00, m01, m10, m11; };
__device__ __forceinline__ mob mmul(const mob& A, const mob& B) {
    mob C;
    C.m00 = caddc(cmulc(A.m00, B.m00), cmulc(A.m01, B.m10));
    C.m01 = caddc(cmulc(A.m00, B.m01), cmulc(A.m01, B.m11));
    C.m10 = caddc(cmulc(A.m10, B.m00), cmulc(A.m11, B.m10));
    C.m11 = caddc(cmulc(A.m10, B.m01), cmulc(A.m11, B.m11));
    return C;
}
__device__ __forceinline__ void mnorm(mob& A) {
    float s = fabsf(A.m00.x);
    s = fmaxf(s, fabsf(A.m00.y)); s = fmaxf(s, fabsf(A.m01.x)); s = fmaxf(s, fabsf(A.m01.y));
    s = fmaxf(s, fabsf(A.m10.x)); s = fmaxf(s, fabsf(A.m10.y)); s = fmaxf(s, fabsf(A.m11.x));
    s = fmaxf(s, fabsf(A.m11.y));
    float r = 1.f / fmaxf(s, 1e-30f);
    A.m00.x *= r; A.m00.y *= r; A.m01.x *= r; A.m01.y *= r;
    A.m10.x *= r; A.m10.y *= r; A.m11.x *= r; A.m11.y *= r;
}
__device__ __forceinline__ mob mstep(cplx a, const mob& P) {
    mob C;
    C.m00 = {a.x*P.m00.x - a.y*P.m00.y - P.m10.x, a.x*P.m00.y + a.y*P.m00.x - P.m10.y};
    C.m01 = {a.x*P.m01.x - a.y*P.m01.y - P.m11.x, a.x*P.m01.y + a.y*P.m01.x - P.m11.y};
    C.m10 = P.m00; C.m11 = P.m01;
    return C;
}
__device__ __forceinline__ void mstore(float* s, const mob& A) {
    s[0]=A.m00.x; s[1]=A.m00.y; s[2]=A.m01.x; s[3]=A.m01.y;
    s[4]=A.m10.x; s[5]=A.m10.y; s[6]=A.m11.x; s[7]=A.m11.y;
}
__device__ __forceinline__ mob mload(const float* s) {
    mob A;
    A.m00 = {s[0], s[1]}; A.m01 = {s[2], s[3]};
    A.m10 = {s[4], s[5]}; A.m11 = {s[6], s[7]};
    return A;
}

// ---------- K0b: fp32 -> bf16 bulk convert (8 elems/thread) ----------
__global__ __launch_bounds__(256) void cvt_kernel(
    const float* __restrict__ src, ushort* __restrict__ dst, int n8)
{
    int i = blockIdx.x * 256 + threadIdx.x;
    if (i >= n8) return;
    const float4* s = ((const float4*)src) + (size_t)i * 2;
    float4 a = s[0], b = s[1];
    uint4 o;
    o.x = pk2(a.x, a.y); o.y = pk2(a.z, a.w);
    o.z = pk2(b.x, b.y); o.w = pk2(b.z, b.w);
    *(((uint4*)dst) + i) = o;
}

// ---------- K0c: fp32 [R][C] -> bf16 transposed [C][R], per-expert (blockIdx.z) ----------
__global__ __launch_bounds__(256) void tcvt_kernel(
    const float* __restrict__ src, ushort* __restrict__ dst, int R, int C)
{
    size_t eoff = (size_t)blockIdx.z * R * C;
    const float* s = src + eoff;
    ushort* d = dst + eoff;
    __shared__ float t[32][33];
    int c0 = blockIdx.x * 32, r0 = blockIdx.y * 32;
    int tid = threadIdx.x;
    int tr = tid >> 3, tc = (tid & 7) * 4;
    float4 vsrc = *(const float4*)(s + (size_t)(r0 + tr) * C + c0 + tc);
    t[tr][tc] = vsrc.x; t[tr][tc+1] = vsrc.y; t[tr][tc+2] = vsrc.z; t[tr][tc+3] = vsrc.w;
    __syncthreads();
    ushort4 o;
    o.x = f2b(t[tc  ][tr]);
    o.y = f2b(t[tc+1][tr]);
    o.z = f2b(t[tc+2][tr]);
    o.w = f2b(t[tc+3][tr]);
    *(ushort4*)(d + (size_t)(c0 + tr) * R + r0 + tc) = o;
}

// ---------- K1: routing (one wave per token), fp32 inputs, NO atomics ----------
__global__ __launch_bounds__(256) void routing_kernel(
    const float* __restrict__ x, const float* __restrict__ v_w, const float* __restrict__ v_b,
    const float* __restrict__ gate_w, const float* __restrict__ gate_b,
    float* __restrict__ v_out, int* __restrict__ tok_e, float* __restrict__ tok_w)
{
    int wave = threadIdx.x >> 6, lane = threadIdx.x & 63;
    int t = blockIdx.x * 4 + wave;
    const float* xr = x + (size_t)t * DD;
    float av = 0.f;
    float ag[8] = {0.f, 0.f, 0.f, 0.f, 0.f, 0.f, 0.f, 0.f};
    #pragma unroll
    for (int i = 0; i < 12; i++) {
        int d = lane + 64 * i;
        float xv = xr[d];
        av += xv * v_w[d];
        const float4* g = (const float4*)(gate_w + d * 8);
        float4 g0 = g[0], g1 = g[1];
        ag[0] += xv * g0.x; ag[1] += xv * g0.y; ag[2] += xv * g0.z; ag[3] += xv * g0.w;
        ag[4] += xv * g1.x; ag[5] += xv * g1.y; ag[6] += xv * g1.z; ag[7] += xv * g1.w;
    }
    #pragma unroll
    for (int off = 32; off >= 1; off >>= 1) {
        av += __shfl_xor(av, off);
        #pragma unroll
        for (int e = 0; e < 8; e++) ag[e] += __shfl_xor(ag[e], off);
    }
    if (lane == 0) {
        float vv = av + v_b[0];
        vv = fminf(fmaxf(vv, -3.f), 3.f);
        v_out[t] = vv;
        float lg[8];
        #pragma unroll
        for (int e = 0; e < 8; e++) lg[e] = ag[e] + gate_b[e];
        int e0 = 0;
        #pragma unroll
        for (int e = 1; e < 8; e++) if (lg[e] > lg[e0]) e0 = e;
        int e1 = -1;
        #pragma unroll
        for (int e = 0; e < 8; e++) if (e != e0 && (e1 < 0 || lg[e] > lg[e1])) e1 = e;
        float w0 = 1.f / (1.f + __expf(lg[e1] - lg[e0]));
        tok_e[2*t] = e0; tok_e[2*t+1] = e1;
        tok_w[2*t] = w0; tok_w[2*t+1] = 1.f - w0;
    }
}

// ---------- K2: fused histogram + bases + tile map + scatter (1 block, LDS atomics only) ----------
__global__ __launch_bounds__(1024) void setup_scatter_kernel(
    const int* __restrict__ tok_e, const float* __restrict__ tok_w,
    int* __restrict__ ctrl, int* __restrict__ row_token, float* __restrict__ row_w,
    int* __restrict__ slot)
{
    __shared__ int cnt[8], base[8], cursor[8];
    int tid = threadIdx.x;
    int lane = tid & 63;
    if (tid < 8) { cnt[tid] = 0; cursor[tid] = 0; }
    __syncthreads();

    int mye[8];
    #pragma unroll
    for (int it = 0; it < 8; it++) {
        int idx = it * 1024 + tid;
        int e = tok_e[idx];
        mye[it] = e;
        #pragma unroll
        for (int ex = 0; ex < 8; ex++) {
            unsigned long long m = __ballot(e == ex);
            if (e == ex && lane == (__ffsll((long long)m) - 1))
                atomicAdd(&cnt[ex], (int)__popcll(m));
        }
    }
    __syncthreads();
    if (tid == 0) {
        int b = 0;
        int* te = ctrl + 24;
        for (int i = 0; i < TILES; i++) te[i] = -1;
        #pragma unroll
        for (int e = 0; e < EE; e++) {
            base[e] = b;
            ctrl[16 + e] = b;
            int tiles = (cnt[e] + 127) >> 7;
            int t0 = b >> 7;
            for (int i = 0; i < tiles; i++) te[t0 + i] = e;
            b += tiles << 7;
        }
    }
    // pad rows default: token -1
    for (int p = tid; p < ROWS_CAP; p += 1024) row_token[p] = -1;
    __syncthreads();

    #pragma unroll
    for (int it = 0; it < 8; it++) {
        int idx = it * 1024 + tid;
        int e = mye[it];
        unsigned long long lt = (1ull << lane) - 1ull;
        int p = 0;
        #pragma unroll
        for (int ex = 0; ex < 8; ex++) {
            unsigned long long m = __ballot(e == ex);
            if (e == ex) {
                int leader = __ffsll((long long)m) - 1;
                int pos = (int)__popcll(m & lt);
                int bp = 0;
                if (lane == leader) bp = atomicAdd(&cursor[ex], (int)__popcll(m));
                bp = __shfl(bp, leader);
                p = base[ex] + bp + pos;
            }
        }
        row_token[p] = idx >> 1;
        row_w[p] = tok_w[idx];
        slot[idx] = p;
    }
}

// ---------- K4: BK Green diag via Mobius prefix scan ----------
__global__ __launch_bounds__(256) void bk_scan_kernel(const float* __restrict__ v, float* __restrict__ feats) {
    int b = blockIdx.x;
    int t = threadIdx.x;
    __shared__ float sm[256][8];
    const mob I = {{1.f,0.f},{0.f,0.f},{0.f,0.f},{1.f,0.f}};
    cplx a[8];
    const float* vb = v + (size_t)b * NN;
    #pragma unroll
    for (int j = 0; j < 8; j++) { a[j].x = -2.f + vb[t*8 + j]; a[j].y = -1.f; }

    mob cur = I;
    #pragma unroll
    for (int j = 0; j < 8; j++) cur = mstep(a[j], cur);
    mnorm(cur);
    mstore(sm[t], cur);
    for (int s = 1; s < 256; s <<= 1) {
        __syncthreads();
        mob prev; bool has = (t >= s);
        if (has) prev = mload(sm[t - s]);
        __syncthreads();
        if (has) { cur = mmul(cur, prev); mnorm(cur); mstore(sm[t], cur); }
    }
    __syncthreads();
    mob P = (t > 0) ? mload(sm[t - 1]) : I;
    cplx dreg[8];
    #pragma unroll
    for (int j = 0; j < 8; j++) {
        P = mstep(a[j], P); mnorm(P);
        dreg[j] = cdivc(P.m00, P.m10);
    }
    __syncthreads();

    cur = I;
    #pragma unroll
    for (int j = 7; j >= 0; j--) cur = mstep(a[j], cur);
    mnorm(cur);
    mstore(sm[t], cur);
    for (int s = 1; s < 256; s <<= 1) {
        __syncthreads();
        mob nxt; bool has = (t + s < 256);
        if (has) nxt = mload(sm[t + s]);
        __syncthreads();
        if (has) { cur = mmul(cur, nxt); mnorm(cur); mstore(sm[t], cur); }
    }
    __syncthreads();
    P = (t < 255) ? mload(sm[t + 1]) : I;
    #pragma unroll
    for (int j = 7; j >= 0; j--) {
        P = mstep(a[j], P); mnorm(P);
        cplx e = cdivc(P.m00, P.m10);
        cplx den = {dreg[j].x + e.x - a[j].x, dreg[j].y + e.y - a[j].y};
        cplx one = {1.f, 0.f};
        cplx G = cdivc(one, den);
        int i = b * NN + t*8 + j;
        feats[2*i]   = G.x;
        feats[2*i+1] = G.y;
    }
}

// ---------- K5: GEMM1  H = gelu(Xg @ w1t[e]^T + b1[e])  — both operands K-major ----------
__global__ __launch_bounds__(256) void gemm1_kernel(
    const ushort* __restrict__ x_bf, const ushort* __restrict__ w1t, const float* __restrict__ b1,
    const int* __restrict__ ctrl, const int* __restrict__ row_token, ushort* __restrict__ H)
{
    int tile = blockIdx.x;
    int e = ctrl[24 + tile];
    if (e < 0) return;
    int p0 = tile * 128;
    int f0 = blockIdx.y * 128;

    __shared__ ushort As[128 * 32];
    __shared__ ushort Bs[128 * 32];
    __shared__ int toks[128];

    int tid = threadIdx.x;
    if (tid < 128) { int tk = row_token[p0 + tid]; toks[tid] = tk < 0 ? 0 : tk; }
    __syncthreads();

    int wave = tid >> 6, lane = tid & 63;
    int rsub = lane >> 2;            // row within 16-row issue
    int kq = (lane & 3) * 8;         // k offset (ushorts)
    int tokA0 = toks[wave*32 + rsub];
    int tokA1 = toks[wave*32 + 16 + rsub];
    const ushort* aglob0 = x_bf + (size_t)tokA0 * DD + kq;
    const ushort* aglob1 = x_bf + (size_t)tokA1 * DD + kq;
    const ushort* w1e = w1t + (size_t)e * (FF * DD);      // [f][d] row stride DD
    const ushort* bglob0 = w1e + (size_t)(f0 + wave*32 + rsub) * DD + kq;
    const ushort* bglob1 = bglob0 + (size_t)16 * DD;
    ushort* AsW = As + wave * 32 * 32;
    ushort* BsW = Bs + wave * 32 * 32;

    floatx4 zero4 = {0.f, 0.f, 0.f, 0.f};
    floatx4 acc[4][4];
    #pragma unroll
    for (int i = 0; i < 4; i++)
        #pragma unroll
        for (int j = 0; j < 4; j++) acc[i][j] = zero4;

    int wm = (wave & 1) * 64, wn = (wave >> 1) * 64;
    int lm = lane & 15, q = lane >> 4;

    for (int k0 = 0; k0 < DD; k0 += 32) {
        gload16(aglob0 + k0, AsW);
        gload16(aglob1 + k0, AsW + 16*32);
        gload16(bglob0 + k0, BsW);
        gload16(bglob1 + k0, BsW + 16*32);
        __syncthreads();
        bf16x8 afr[4], bfr[4];
        #pragma unroll
        for (int i = 0; i < 4; i++)
            afr[i] = *(const bf16x8*)(const void*)(As + (wm + i*16 + lm) * 32 + q*8);
        #pragma unroll
        for (int j = 0; j < 4; j++)
            bfr[j] = *(const bf16x8*)(const void*)(Bs + (wn + j*16 + lm) * 32 + q*8);
        #pragma unroll
        for (int i = 0; i < 4; i++)
            #pragma unroll
            for (int j = 0; j < 4; j++)
                acc[i][j] = __builtin_amdgcn_mfma_f32_16x16x32_bf16(afr[i], bfr[j], acc[i][j], 0, 0, 0);
        __syncthreads();
    }
    #pragma unroll
    for (int i = 0; i < 4; i++) {
        #pragma unroll
        for (int j = 0; j < 4; j++) {
            int n = wn + j*16 + lm;
            float bias = b1[e * FF + f0 + n];
            #pragma unroll
            for (int r = 0; r < 4; r++) {
                int m = wm + i*16 + q*4 + r;
                float hv = gelu_f(acc[i][j][r] + bias);
                H[(size_t)(p0 + m) * FF + f0 + n] = f2b(hv);
            }
        }
    }
}

// ---------- K6: GEMM2  Y = row_w * (H @ w2t[e]^T + b2[e]) ----------
__global__ __launch_bounds__(256) void gemm2_kernel(
    const ushort* __restrict__ H, const ushort* __restrict__ w2t, const float* __restrict__ b2,
    const int* __restrict__ ctrl, const float* __restrict__ row_w, float* __restrict__ Y)
{
    int tile = blockIdx.x;
    int e = ctrl[24 + tile];
    if (e < 0) return;
    int p0 = tile * 128;
    int d0 = blockIdx.y * 128;

    __shared__ ushort As[128 * 32];
    __shared__ ushort Bs[128 * 32];

    int tid = threadIdx.x;
    int wave = tid >> 6, lane = tid & 63;
    int rsub = lane >> 2;
    int kq = (lane & 3) * 8;
    const ushort* aglob0 = H + (size_t)(p0 + wave*32 + rsub) * FF + kq;
    const ushort* aglob1 = aglob0 + (size_t)16 * FF;
    const ushort* w2e = w2t + (size_t)e * (DD * FF);      // [d][f] row stride FF
    const ushort* bglob0 = w2e + (size_t)(d0 + wave*32 + rsub) * FF + kq;
    const ushort* bglob1 = bglob0 + (size_t)16 * FF;
    ushort* AsW = As + wave * 32 * 32;
    ushort* BsW = Bs + wave * 32 * 32;

    floatx4 zero4 = {0.f, 0.f, 0.f, 0.f};
    floatx4 acc[4][4];
    #pragma unroll
    for (int i = 0; i < 4; i++)
        #pragma unroll
        for (int j = 0; j < 4; j++) acc[i][j] = zero4;

    int wm = (wave & 1) * 64, wn = (wave >> 1) * 64;
    int lm = lane & 15, q = lane >> 4;

    for (int k0 = 0; k0 < FF; k0 += 32) {
        gload16(aglob0 + k0, AsW);
        gload16(aglob1 + k0, AsW + 16*32);
        gload16(bglob0 + k0, BsW);
        gload16(bglob1 + k0, BsW + 16*32);
        __syncthreads();
        bf16x8 afr[4], bfr[4];
        #pragma unroll
        for (int i = 0; i < 4; i++)
            afr[i] = *(const bf16x8*)(const void*)(As + (wm + i*16 + lm) * 32 + q*8);
        #pragma unroll
        for (int j = 0; j < 4; j++)
            bfr[j] = *(const bf16x8*)(const void*)(Bs + (wn + j*16 + lm) * 32 + q*8);
        #pragma unroll
        for (int i = 0; i < 4; i++)
            #pragma unroll
            for (int j = 0; j < 4; j++)
                acc[i][j] = __builtin_amdgcn_mfma_f32_16x16x32_bf16(afr[i], bfr[j], acc[i][j], 0, 0, 0);
        __syncthreads();
    }
    #pragma unroll
    for (int i = 0; i < 4; i++) {
        #pragma unroll
        for (int j = 0; j < 4; j++) {
            int n = wn + j*16 + lm;
            float bias = b2[e * DD + d0 + n];
            #pragma unroll
            for (int r = 0; r < 4; r++) {
                int m = wm + i*16 + q*4 + r;
                float wgt = row_w[p0 + m];
                Y[(size_t)(p0 + m) * DD + d0 + n] = wgt * (acc[i][j][r] + bias);
            }
        }
    }
}

// ---------- K7: final combine (fp32 out) ----------
__global__ __launch_bounds__(256) void final_kernel(
    const float* __restrict__ Y, const int* __restrict__ slot, const float* __restrict__ feats,
    const float* __restrict__ out_w, const float* __restrict__ out_b,
    const float* __restrict__ bk_scale, float* __restrict__ out)
{
    int idx = blockIdx.x * 256 + threadIdx.x;
    int base = idx * 4;
    int t = base / DD;
    int d = base - t * DD;
    int p0 = slot[2*t], p1 = slot[2*t + 1];
    const float4 ya = *(const float4*)(Y + (size_t)p0 * DD + d);
    const float4 yb = *(const float4*)(Y + (size_t)p1 * DD + d);
    float f0 = feats[2*t], f1 = feats[2*t + 1];
    f0 = fminf(fmaxf(f0, -10.f), 10.f);
    f1 = fminf(fmaxf(f1, -10.f), 10.f);
    float ff[4] = {ya.x + yb.x, ya.y + yb.y, ya.z + yb.z, ya.w + yb.w};
    float4 o;
    float* op = (float*)&o;
    #pragma unroll
    for (int u = 0; u < 4; u++) {
        float spec = f0 * out_w[d + u] + f1 * out_w[DD + d + u] + out_b[d + u];
        op[u] = ff[u] + bk_scale[d + u] * spec;
    }
    *(float4*)(out + base) = o;
}

extern "C" void kernel_launch(void* const* d_in, const int* in_sizes, int n_in,
                              void* d_out, int out_size, void* d_ws, size_t ws_size,
                              hipStream_t stream)
{
    const float* x      = (const float*)d_in[0];
    const float* v_w    = (const float*)d_in[1];
    const float* v_b    = (const float*)d_in[2];
    const float* gate_w = (const float*)d_in[3];
    const float* gate_b = (const float*)d_in[4];
    const float* w1     = (const float*)d_in[5];
    const float* b1     = (const float*)d_in[6];
    const float* w2     = (const float*)d_in[7];
    const float* b2     = (const float*)d_in[8];
    const float* out_w  = (const float*)d_in[9];
    const float* out_b  = (const float*)d_in[10];
    const float* bk_s   = (const float*)d_in[11];

    char* ws = (char*)d_ws;
    int*    ctrl    = (int*)(ws + OFF_CTRL);
    float*  v       = (float*)(ws + OFF_V);
    int*    tok_e   = (int*)(ws + OFF_TOKE);
    float*  tok_w   = (float*)(ws + OFF_TOKW);
    int*    row_tok = (int*)(ws + OFF_ROWTOK);
    float*  row_w   = (float*)(ws + OFF_ROWW);
    int*    slot    = (int*)(ws + OFF_SLOT);
    float*  feats   = (float*)(ws + OFF_FEATS);
    ushort* w2t     = (ushort*)(ws + OFF_W2T);
    ushort* x_bf    = (ushort*)(ws + OFF_XBF);
    ushort* w1t     = (ushort*)(ws + OFF_W1T);
    ushort* H       = (ushort*)(ws + OFF_H);
    float*  Y       = (float*)(ws + OFF_Y);
    float*  out     = (float*)d_out;

    cvt_kernel<<<(TOK*DD)/8/256, 256, 0, stream>>>(x, x_bf, (TOK*DD)/8);
    // w1: [e][768][3072] -> w1t [e][3072][768]
    tcvt_kernel<<<dim3(FF/32, DD/32, EE), 256, 0, stream>>>(w1, w1t, DD, FF);
    // w2: [e][3072][768] -> w2t [e][768][3072]
    tcvt_kernel<<<dim3(DD/32, FF/32, EE), 256, 0, stream>>>(w2, w2t, FF, DD);
    routing_kernel<<<TOK / 4, 256, 0, stream>>>(x, v_w, v_b, gate_w, gate_b, v, tok_e, tok_w);
    setup_scatter_kernel<<<1, 1024, 0, stream>>>(tok_e, tok_w, ctrl, row_tok, row_w, slot);
    bk_scan_kernel<<<BB, 256, 0, stream>>>(v, feats);
    gemm1_kernel<<<dim3(TILES, FF / 128), 256, 0, stream>>>(x_bf, w1t, b1, ctrl, row_tok, H);
    gemm2_kernel<<<dim3(TILES, DD / 128), 256, 0, stream>>>(H, w2t, b2, ctrl, row_w, Y);
    final_kernel<<<(TOK * DD) / 1024, 256, 0, stream>>>(Y, slot, feats, out_w, out_b, bk_s, out);
}